// Round 17
// baseline (75.349 us; speedup 1.0000x reference)
//
#include <hip/hip_runtime.h>
#include <hip/hip_fp16.h>
#include <math.h>

#define XD 128
#define YD 128
#define ZD 96
#define NV (XD*YD*ZD)      /* 1572864 voxels per volume */
#define SXX (YD*ZD)        /* x-stride = 12288 */
#define SENT 49152         /* sentinel: > any real d^2 (max 41283) */
#define TW2 114            /* u16 cols: 8 pad | 96 z | 10 pad; 57 dw, 57%32=25 */
#define TDW (TW2/2)        /* 57 dwords per row */
#define TROWS 144          /* rows: 8 pad | 128 y | 8 pad */
#define SCANB 192          /* scan blocks per batch */
#define PROBB 1024         /* prob blocks per batch: 1024*384 = NV/4 exactly */

// -------- block-specialized: scan blocks + softmax blocks, one dispatch ----
__global__ __launch_bounds__(384) void k_scan_prob(const int* __restrict__ gt,
                                                   const float* __restrict__ net,
                                                   unsigned char* __restrict__ out,
                                                   __half2* __restrict__ probs,
                                                   int* __restrict__ flags,
                                                   int batch0) {
    const int bb  = blockIdx.y;
    const int myb = batch0 + bb;
    const int tid = threadIdx.x;

    if (blockIdx.x >= SCANB) {           // ---------------- prob role ----
        const int p = (blockIdx.x - SCANB) * 384 + tid;   // quad index < NV/4
        const int idx = p * 4;
        const float* nb = net + (size_t)myb * 4 * NV;
        float4 v0 = *(const float4*)(nb + idx);
        float4 v1 = *(const float4*)(nb + NV + idx);
        float4 v2 = *(const float4*)(nb + 2 * NV + idx);
        float4 v3 = *(const float4*)(nb + 3 * NV + idx);

        const float a0[4] = {v0.x, v0.y, v0.z, v0.w};
        const float a1[4] = {v1.x, v1.y, v1.z, v1.w};
        const float a2[4] = {v2.x, v2.y, v2.z, v2.w};
        const float a3[4] = {v3.x, v3.y, v3.z, v3.w};
        float p1[4], p2[4], p3[4];
#pragma unroll
        for (int j = 0; j < 4; ++j) {
            float mx = fmaxf(fmaxf(a0[j], a1[j]), fmaxf(a2[j], a3[j]));
            float e0 = __expf(a0[j] - mx);
            float e1 = __expf(a1[j] - mx);
            float e2 = __expf(a2[j] - mx);
            float e3 = __expf(a3[j] - mx);
            float iv = __frcp_rn(e0 + e1 + e2 + e3);
            p1[j] = e1 * iv; p2[j] = e2 * iv; p3[j] = e3 * iv;
        }
        __half2 h10 = __floats2half2_rn(p1[0], p1[1]);
        __half2 h11 = __floats2half2_rn(p1[2], p1[3]);
        __half2 h20 = __floats2half2_rn(p2[0], p2[1]);
        __half2 h21 = __floats2half2_rn(p2[2], p2[3]);
        __half2 h30 = __floats2half2_rn(p3[0], p3[1]);
        __half2 h31 = __floats2half2_rn(p3[2], p3[3]);
        ((__half2*)probs)[(size_t)(myb * 3 + 0) * (NV / 2) + 2 * p]     = h10;
        ((__half2*)probs)[(size_t)(myb * 3 + 0) * (NV / 2) + 2 * p + 1] = h11;
        ((__half2*)probs)[(size_t)(myb * 3 + 1) * (NV / 2) + 2 * p]     = h20;
        ((__half2*)probs)[(size_t)(myb * 3 + 1) * (NV / 2) + 2 * p + 1] = h21;
        ((__half2*)probs)[(size_t)(myb * 3 + 2) * (NV / 2) + 2 * p]     = h30;
        ((__half2*)probs)[(size_t)(myb * 3 + 2) * (NV / 2) + 2 * p + 1] = h31;
        return;
    }

    // ---------------- scan role ----
    const int l   = tid & 63;
    const int w6  = tid >> 6;            // 0..5
    const int lq0 = blockIdx.x * 64;

    __shared__ unsigned char gtile[64 * 132];
    __shared__ int blkbits;
    if (tid == 0) blkbits = 0;

    int mybits = 0;
    const int* gp = gt + (size_t)myb * NV + lq0 + l;
    for (int j = w6; j < XD; j += 6) {
        int g = gp[(size_t)j * SXX];
        mybits |= 1 << g;
        gtile[l * 132 + j] = (unsigned char)g;
    }
#pragma unroll
    for (int off = 32; off; off >>= 1) mybits |= __shfl_xor(mybits, off);
    __syncthreads();
    if ((tid & 63) == 0) atomicOr(&blkbits, mybits);

    unsigned int D[32];
    {   // thread = (slot w6, line l); all in registers
        const unsigned int ci = (unsigned int)((w6 >> 1) + 1);
        const int s = w6 & 1;
        unsigned int G[32];
        const unsigned int* grow = (const unsigned int*)gtile + l * 33;
#pragma unroll
        for (int q = 0; q < 32; ++q) G[q] = grow[q];

        int cnt = 200;
#pragma unroll
        for (int q = 0; q < 32; ++q) {
            unsigned int u = G[q], dv = 0;
#pragma unroll
            for (int b = 0; b < 4; ++b) {
                unsigned int gv = (u >> (8 * b)) & 255u;
                bool zero = s ? (gv == ci) : (gv != ci);
                cnt = zero ? 0 : ((cnt < 200) ? cnt + 1 : 200);
                dv |= (unsigned int)cnt << (8 * b);
            }
            D[q] = dv;
        }
        cnt = 200;
#pragma unroll
        for (int q = 31; q >= 0; --q) {
            unsigned int u = G[q], dv = D[q];
#pragma unroll
            for (int b = 3; b >= 0; --b) {
                unsigned int gv = (u >> (8 * b)) & 255u;
                bool zero = s ? (gv == ci) : (gv != ci);
                cnt = zero ? 0 : ((cnt < 200) ? cnt + 1 : 200);
                unsigned int old = (dv >> (8 * b)) & 255u;
                unsigned int nbv = ((unsigned int)cnt < old) ? (unsigned int)cnt : old;
                dv = (dv & ~(255u << (8 * b))) | (nbv << (8 * b));
            }
            D[q] = dv;
        }
    }
    __syncthreads();                     // blkbits complete
    if (tid == 0) atomicOr(&flags[myb], blkbits);

    // in-wave 4x4 byte transpose (groups of 4 lanes = 4 lines) + store
    {
        const int r = l & 3;
        unsigned char* ob = out + (size_t)(bb * 6 + w6) * NV + lq0 + (l & ~3);
#pragma unroll
        for (int q = 0; q < 32; ++q) {
            unsigned int A = D[q];
            unsigned int Bv = (unsigned int)__shfl_xor((int)A, 1);
            unsigned int t = (r & 1)
                ? __builtin_amdgcn_perm(A, Bv, 0x07030501u)
                : __builtin_amdgcn_perm(A, Bv, 0x02060004u);
            unsigned int Cv = (unsigned int)__shfl_xor((int)t, 2);
            unsigned int y = (r & 2)
                ? __builtin_amdgcn_perm(t, Cv, 0x07060302u)
                : __builtin_amdgcn_perm(t, Cv, 0x01000504u);
            *(unsigned int*)(ob + (size_t)(4 * q + r) * SXX) = y;
        }
    }
}

// ------------- EDT fast path: t<=8 on a 32-float register window -----------
__device__ __forceinline__ bool edt_fast(const float r[32], float m[16]) {
#pragma unroll
    for (int k = 0; k < 16; ++k) m[k] = r[k + 8];
#pragma unroll
    for (int t = 1; t <= 4; ++t) {
        const float t2 = (float)(t * t);
#pragma unroll
        for (int k = 0; k < 16; ++k)
            m[k] = fminf(m[k], fminf(r[k + 8 - t], r[k + 8 + t]) + t2);
    }
    float mm = m[0];
#pragma unroll
    for (int k = 1; k < 16; ++k) mm = fmaxf(mm, m[k]);
    if (__all(mm <= 16.0f)) return true;
#pragma unroll
    for (int t = 5; t <= 8; ++t) {
        const float t2 = (float)(t * t);
#pragma unroll
        for (int k = 0; k < 16; ++k)
            m[k] = fminf(m[k], fminf(r[k + 8 - t], r[k + 8 + t]) + t2);
    }
    mm = m[0];
#pragma unroll
    for (int k = 1; k < 16; ++k) mm = fmaxf(mm, m[k]);
    return __all(mm <= 64.0f) != 0;
}

// ------- EDT slow path (rare): FORCE-INLINED so m[] stays in registers -----
// (a non-inlined call makes the array params decay to memory -> scratch)
template<int STRIDE, int L>
__device__ __forceinline__ void edt_slow(const unsigned short* __restrict__ p0,
                                         int i0, float m[16]) {
    int t = 9;
    bool done = false;
    while (!done && t < L) {
        for (int u = 0; u < 4; ++u, ++t) {
            float t2 = (float)(t * t);
#pragma unroll
            for (int k = 0; k < 16; ++k) {
                int jm = i0 + k - t; if (jm < -8) jm = -8;
                int jp = i0 + k + t; if (jp > L + 7) jp = L + 7;
                m[k] = fminf(m[k], fminf((float)p0[jm * STRIDE],
                                         (float)p0[jp * STRIDE]) + t2);
            }
        }
        float mm = m[0];
#pragma unroll
        for (int k = 1; k < 16; ++k) mm = fmaxf(mm, m[k]);
        done = __all(mm <= (float)((t - 1) * (t - 1))) != 0;
    }
}

// ------ fused Y+Z EDT + loss accumulation: one (x, class, batch) block -----
// No min-waves bound: let the allocator use the ~70 VGPRs the inlined EDT
// needs (the old (768,6) bound forced 40 VGPRs -> 23 MB scratch, 1% VALU).
__global__ __launch_bounds__(768) void k_yz_acc(const unsigned char* __restrict__ in,
                                                const __half2* __restrict__ probs,
                                                const int* __restrict__ flags,
                                                double* __restrict__ partials,
                                                int batch0) {
    const int x   = blockIdx.x;
    const int bbl = blockIdx.y / 3;      // local batch (xbuf slot group)
    const int c   = blockIdx.y % 3;      // class-1
    const int b   = batch0 + bbl;        // global batch
    const int tid = threadIdx.x;
    const int pidx = (b * 3 + c) * XD + x;

    __shared__ unsigned short tile[TROWS * TW2];
    __shared__ double sd[768];
    unsigned int* t32 = (unsigned int*)tile;

    if (((flags[b] >> (c + 1)) & 1) == 0) {
        if (tid == 0) partials[pidx] = 0.0;
        return;
    }

    for (int i = tid; i < 16 * TDW; i += 768) {
        int r = i / TDW, cc = i - r * TDW;
        int row = (r < 8) ? r : 128 + r;
        t32[row * TDW + cc] = 0xFFFFFFFFu;
    }
    for (int i = tid; i < 128 * 9; i += 768) {
        int r = i / 9, cc = i - r * 9;
        int col = (cc < 4) ? cc : (48 + cc);
        t32[(8 + r) * TDW + col] = 0xFFFFFFFFu;
    }

    const int z0 = tid % 96;  const int iY = (tid / 96) * 16;
    const int y0 = tid % 128; const int iZ = (tid / 128) * 16;
    const int e  = tid * 16;
    const int sy = e / ZD, sz = e - sy * ZD;
    const unsigned int sbase = (8 + sy) * TDW + (8 + sz) / 2;

    float m[16];
    unsigned int dpp[8];

    // ================= pos plane (slot 2c) =================
    {
        const uint4* ip = (const uint4*)(in + (size_t)(bbl * 6 + 2 * c) * NV +
                                         (size_t)x * SXX);
        uint4 v = ip[tid];
        unsigned int vv[4] = {v.x, v.y, v.z, v.w};
#pragma unroll
        for (int q = 0; q < 4; ++q) {
            unsigned int b0 = vv[q] & 255u, b1 = (vv[q] >> 8) & 255u;
            unsigned int b2 = (vv[q] >> 16) & 255u, b3 = vv[q] >> 24;
            t32[sbase + 2 * q] = (b0 > 127u ? SENT : b0 * b0) |
                                 ((b1 > 127u ? SENT : b1 * b1) << 16);
            t32[sbase + 2 * q + 1] = (b2 > 127u ? SENT : b2 * b2) |
                                     ((b3 > 127u ? SENT : b3 * b3) << 16);
        }
    }
    __syncthreads();
    {   // Y phase
        float r[32];
#pragma unroll
        for (int w = 0; w < 32; ++w) r[w] = (float)tile[(iY + w) * TW2 + 8 + z0];
        if (!edt_fast(r, m)) edt_slow<TW2, YD>(&tile[8 * TW2 + 8 + z0], iY, m);
        __syncthreads();
#pragma unroll
        for (int k = 0; k < 16; ++k)
            tile[(8 + iY + k) * TW2 + 8 + z0] =
                (unsigned short)fminf(m[k], (float)SENT);
        __syncthreads();
    }
    {   // Z phase (result kept in regs; no write-back)
        float r[32];
        const unsigned int* wp = &t32[(8 + y0) * TDW + iZ / 2];
#pragma unroll
        for (int q = 0; q < 16; ++q) {
            unsigned int u = wp[q];
            r[2 * q] = (float)(u & 0xFFFFu);
            r[2 * q + 1] = (float)(u >> 16);
        }
        if (!edt_fast(r, m)) edt_slow<1, ZD>(&tile[(8 + y0) * TW2 + 8], iZ, m);
    }
#pragma unroll
    for (int q = 0; q < 8; ++q)
        dpp[q] = (unsigned int)fminf(m[2 * q], (float)SENT) |
                 ((unsigned int)fminf(m[2 * q + 1], (float)SENT) << 16);
    __syncthreads();                     // all pos-plane reads done

    // ================= neg plane (slot 2c+1), same tile =================
    {
        const uint4* ip = (const uint4*)(in + (size_t)(bbl * 6 + 2 * c + 1) * NV +
                                         (size_t)x * SXX);
        uint4 v = ip[tid];
        unsigned int vv[4] = {v.x, v.y, v.z, v.w};
#pragma unroll
        for (int q = 0; q < 4; ++q) {
            unsigned int b0 = vv[q] & 255u, b1 = (vv[q] >> 8) & 255u;
            unsigned int b2 = (vv[q] >> 16) & 255u, b3 = vv[q] >> 24;
            t32[sbase + 2 * q] = (b0 > 127u ? SENT : b0 * b0) |
                                 ((b1 > 127u ? SENT : b1 * b1) << 16);
            t32[sbase + 2 * q + 1] = (b2 > 127u ? SENT : b2 * b2) |
                                     ((b3 > 127u ? SENT : b3 * b3) << 16);
        }
    }
    __syncthreads();
    {   // Y phase
        float r[32];
#pragma unroll
        for (int w = 0; w < 32; ++w) r[w] = (float)tile[(iY + w) * TW2 + 8 + z0];
        if (!edt_fast(r, m)) edt_slow<TW2, YD>(&tile[8 * TW2 + 8 + z0], iY, m);
        __syncthreads();
#pragma unroll
        for (int k = 0; k < 16; ++k)
            tile[(8 + iY + k) * TW2 + 8 + z0] =
                (unsigned short)fminf(m[k], (float)SENT);
        __syncthreads();
    }
    {   // Z phase -> m = dn^2
        float r[32];
        const unsigned int* wp = &t32[(8 + y0) * TDW + iZ / 2];
#pragma unroll
        for (int q = 0; q < 16; ++q) {
            unsigned int u = wp[q];
            r[2 * q] = (float)(u & 0xFFFFu);
            r[2 * q + 1] = (float)(u >> 16);
        }
        if (!edt_fast(r, m)) edt_slow<1, ZD>(&tile[(8 + y0) * TW2 + 8], iZ, m);
    }

    // ================= accumulate p * phi =================
    float a = 0.0f;
    {
        const __half2* pv = probs + (size_t)(b * 3 + c) * (NV / 2) +
                            ((size_t)x * SXX + (size_t)y0 * ZD + iZ) / 2;
#pragma unroll
        for (int q = 0; q < 8; ++q) {
            float2 pf = __half22float2(pv[q]);
            unsigned int dp0 = dpp[q] & 0xFFFFu, dp1 = dpp[q] >> 16;
            float phi0 = (dp0 == 1u) ? 0.0f
                       : (sqrtf(m[2 * q]) - sqrtf((float)dp0));
            float phi1 = (dp1 == 1u) ? 0.0f
                       : (sqrtf(m[2 * q + 1]) - sqrtf((float)dp1));
            a += pf.x * phi0 + pf.y * phi1;
        }
    }
    sd[tid] = (double)a;
    __syncthreads();
    for (int off = 512; off; off >>= 1) {
        if (tid < off && tid + off < 768) sd[tid] += sd[tid + off];
        __syncthreads();
    }
    if (tid == 0) partials[pidx] = sd[0];
}

// -------------------------------------------------------------- reduce ----
__global__ void k_reduce(const double* __restrict__ partials, int n,
                         float* __restrict__ out) {
    __shared__ double sd[256];
    double ls = 0.0;
    for (int i = threadIdx.x; i < n; i += 256) ls += partials[i];
    sd[threadIdx.x] = ls;
    __syncthreads();
    for (int off = 128; off > 0; off >>= 1) {
        if (threadIdx.x < off) sd[threadIdx.x] += sd[threadIdx.x + off];
        __syncthreads();
    }
    if (threadIdx.x == 0) out[0] = (float)(sd[0] / 9437184.0);
}

// ---------------------------------------------------------------- launch ----
extern "C" void kernel_launch(void* const* d_in, const int* in_sizes, int n_in,
                              void* d_out, int out_size, void* d_ws, size_t ws_size,
                              hipStream_t stream) {
    const float* net = (const float*)d_in[0];
    const int*   gt  = (const int*)d_in[1];
    float* out = (float*)d_out;
    char* ws = (char*)d_ws;

    const size_t xbufB1  = (size_t)6 * NV;               // u8 per batch, 9.4 MB
    const size_t probsB  = (size_t)2 * 3 * NV * 2;       // f16, both batches, 18.9 MB
    const size_t tail    = (size_t)768 * sizeof(double) + 64;

    const int nb = (ws_size >= 2 * xbufB1 + probsB + tail) ? 2 : 1;

    unsigned char* xbuf  = (unsigned char*)ws;
    __half2*       probs = (__half2*)(ws + (size_t)nb * xbufB1);
    double*     partials = (double*)(ws + (size_t)nb * xbufB1 + probsB);
    int*           flags = (int*)((char*)partials + 768 * sizeof(double));

    hipMemsetAsync(flags, 0, 8 * sizeof(int), stream);

    for (int b0 = 0; b0 < 2; b0 += nb) {
        hipLaunchKernelGGL(k_scan_prob, dim3(SCANB + PROBB, nb), dim3(384), 0,
                           stream, gt, net, xbuf, probs, flags, b0);
        hipLaunchKernelGGL(k_yz_acc, dim3(XD, 3 * nb), dim3(768), 0, stream,
                           xbuf, probs, flags, partials, b0);
    }
    hipLaunchKernelGGL(k_reduce, dim3(1), dim3(256), 0, stream, partials,
                       768, out);
}